// Round 9
// baseline (115.339 us; speedup 1.0000x reference)
//
#include <hip/hip_runtime.h>
#include <hip/hip_bf16.h>

// Fused GAT layer, round 9: R8 + W-dedup (wave covers TWO n's with one bfrag set).
// Wave = (n-pair, g-half); block = 4 waves = (n-quad). 2048 blocks. Barrier-free,
// no LDS. Interleaved g-mapping g = half*64 + 4*l15 + gt (float4 W/a_pair/att).
// W L2 traffic halved (512->256 MB): bfrag loaded once per wave serves both n's.
// MFMA 16x16x32 bf16, m89 layout: C col=l15 -> g-group, row=l4*4+r -> k.

#define NK 32768
#define NEG_SLOPE 0.2f

using f32x4 = __attribute__((ext_vector_type(4))) float;
using s16x8 = __attribute__((ext_vector_type(8))) short;

__global__ __launch_bounds__(256, 3) void fused_gat_wave(
    const float* __restrict__ x,
    const int*   __restrict__ core_types,
    const int*   __restrict__ target_types,
    const float* __restrict__ W,
    const float* __restrict__ a_pair,
    float* __restrict__ out,
    float* __restrict__ att_out)
{
    const int t    = threadIdx.x;
    const int lane = t & 63, l15 = lane & 15, l4 = lane >> 4;
    const int wv   = t >> 6;                  // 0..3
    const int pr   = wv >> 1, half = wv & 1;  // wave -> (n-pair, g-half)
    const int b    = blockIdx.x >> 8;
    const int np   = (blockIdx.x & 255) * 4 + 2 * pr;   // first n of the wave's pair

    const float* xb = x + (size_t)b * 128 * NK + np * 32;  // + f*NK + nl2*32 + k
    const int    g0 = half * 64 + 4 * l15;                 // lane's base g; g = g0 + gt
    const float* wb = W + g0;                              // + f*128

    // ---- MFMA fs-loop: acc[nl2][mt][gt], k = 16mt + l4*4 + r, g = g0 + gt
    f32x4 acc[2][2][4];
    #pragma unroll
    for (int nl2 = 0; nl2 < 2; ++nl2)
        #pragma unroll
        for (int mt = 0; mt < 2; ++mt)
            #pragma unroll
            for (int gt = 0; gt < 4; ++gt) acc[nl2][mt][gt] = (f32x4){0.f, 0.f, 0.f, 0.f};

    #pragma unroll
    for (int fs = 0; fs < 4; ++fs) {
        const int f0 = fs * 32 + l4 * 8;

        // W: one float4 per f-row (covers gt=0..3); ONE set serves both n's
        s16x8 bfrag[4];
        #pragma unroll
        for (int fp = 0; fp < 4; ++fp) {                   // f = f0 + 2fp (+1)
            const f32x4 we = *(const f32x4*)&wb[(size_t)(f0 + 2 * fp)     * 128];
            const f32x4 wo = *(const f32x4*)&wb[(size_t)(f0 + 2 * fp + 1) * 128];
            #pragma unroll
            for (int gt = 0; gt < 4; ++gt) {
                __hip_bfloat162 h2 = __float22bfloat162_rn(make_float2(we[gt], wo[gt]));
                ((unsigned*)&bfrag[gt])[fp] = *(const unsigned*)&h2;
            }
        }

        #pragma unroll
        for (int nl2 = 0; nl2 < 2; ++nl2) {
            s16x8 afrag[2];
            #pragma unroll
            for (int mt = 0; mt < 2; ++mt)
                #pragma unroll
                for (int i2 = 0; i2 < 4; ++i2) {
                    const int f = f0 + 2 * i2;
                    __hip_bfloat162 h2 = __float22bfloat162_rn(make_float2(
                        xb[(size_t)f * NK + nl2 * 32 + 16 * mt + l15],
                        xb[(size_t)(f + 1) * NK + nl2 * 32 + 16 * mt + l15]));
                    ((unsigned*)&afrag[mt])[i2] = *(const unsigned*)&h2;
                }
            #pragma unroll
            for (int mt = 0; mt < 2; ++mt)
                #pragma unroll
                for (int gt = 0; gt < 4; ++gt)
                    acc[nl2][mt][gt] = __builtin_amdgcn_mfma_f32_16x16x32_bf16(
                        afrag[mt], bfrag[gt], acc[nl2][mt][gt], 0, 0, 0);
        }
    }

    // ---- epilogue, sequential per n (keeps ev at 32 regs)
    #pragma unroll 1
    for (int nl2 = 0; nl2 < 2; ++nl2) {
        const int n  = np + nl2;
        const int cc = core_types[b * 1024 + n];

        float ev[2][4][4];
        #pragma unroll
        for (int mt = 0; mt < 2; ++mt) {
            const int kb = 16 * mt + l4 * 4;
            const int4 tt4 = *(const int4*)&target_types[((size_t)(b * 1024 + n)) * 32 + kb];
            const int ttv[4] = {tt4.x, tt4.y, tt4.z, tt4.w};
            #pragma unroll
            for (int r = 0; r < 4; ++r) {
                const int tv = ttv[r];
                const int lo = min(cc, tv), hi = max(cc, tv);
                const int idx = lo * (17 - lo) / 2 + (hi - lo);
                const f32x4 a4 = *(const f32x4*)&a_pair[idx * 128 + g0];
                #pragma unroll
                for (int gt = 0; gt < 4; ++gt) {
                    const float e = acc[nl2][mt][gt][r] * a4[gt];
                    ev[mt][gt][r] = e > 0.f ? e : NEG_SLOPE * e;
                }
            }
        }

        // softmax over k (8 regs x 4-lane group: xor 16, 32), per gt
        #pragma unroll
        for (int gt = 0; gt < 4; ++gt) {
            float mx = -1e30f;
            #pragma unroll
            for (int mt = 0; mt < 2; ++mt)
                #pragma unroll
                for (int r = 0; r < 4; ++r) mx = fmaxf(mx, ev[mt][gt][r]);
            mx = fmaxf(mx, __shfl_xor(mx, 16));
            mx = fmaxf(mx, __shfl_xor(mx, 32));
            float sm = 0.f;
            #pragma unroll
            for (int mt = 0; mt < 2; ++mt)
                #pragma unroll
                for (int r = 0; r < 4; ++r) {
                    const float p = __expf(ev[mt][gt][r] - mx);
                    ev[mt][gt][r] = p;
                    sm += p;
                }
            sm += __shfl_xor(sm, 16);
            sm += __shfl_xor(sm, 32);
            const float inv = __fdividef(1.f, sm);
            #pragma unroll
            for (int mt = 0; mt < 2; ++mt)
                #pragma unroll
                for (int r = 0; r < 4; ++r) ev[mt][gt][r] *= inv;
        }

        // stores (non-temporal: write streams never re-read; protect x's L3 residency)
        #pragma unroll
        for (int mt = 0; mt < 2; ++mt) {
            const int kb = 16 * mt + l4 * 4;
            #pragma unroll
            for (int gt = 0; gt < 4; ++gt) {
                f32x4 ov;
                #pragma unroll
                for (int r = 0; r < 4; ++r) {
                    const float hh = ev[mt][gt][r] * acc[nl2][mt][gt][r];
                    ov[r] = hh > 0.f ? hh : __expf(hh) - 1.f;
                }
                __builtin_nontemporal_store(
                    ov, (f32x4*)&out[(size_t)b * 128 * NK + (size_t)(g0 + gt) * NK + n * 32 + kb]);
            }
            #pragma unroll
            for (int r = 0; r < 4; ++r) {
                f32x4 av = {ev[mt][0][r], ev[mt][1][r], ev[mt][2][r], ev[mt][3][r]};
                __builtin_nontemporal_store(
                    av, (f32x4*)&att_out[(((size_t)(b * 1024 + n)) * 32 + kb + r) * 128 + g0]);
            }
        }
    }
}

extern "C" void kernel_launch(void* const* d_in, const int* in_sizes, int n_in,
                              void* d_out, int out_size, void* d_ws, size_t ws_size,
                              hipStream_t stream) {
    const float* x    = (const float*)d_in[0];
    const int*   core = (const int*)  d_in[1];
    const int*   tgt  = (const int*)  d_in[2];
    const float* W    = (const float*)d_in[3];
    const float* ap   = (const float*)d_in[4];
    // d_in[5]/d_in[6] (lin_w, lin_b) only feed attention_viz, which is not returned.

    float* out_p = (float*)d_out;                       // (8,128,1024,32)
    float* att_p = out_p + (size_t)8 * 128 * 1024 * 32; // (8,1024,32,128)

    fused_gat_wave<<<dim3(2048), dim3(256), 0, stream>>>(x, core, tgt, W, ap, out_p, att_p);
}

// Round 10
// 68.448 us; speedup vs baseline: 1.6851x; 1.6851x over previous
//
#include <hip/hip_runtime.h>
#include <hip/hip_bf16.h>

// Fused GAT layer, round 10: R8 compute (barrier-free per-wave MFMA, interleaved
// g-mapping) + LDS-bounced out-stores (64B scattered segments -> 256B contiguous).
// Wave = (b, n, g-half). Block = 4 waves = (n0,n0+1) x 2 halves.
// out-tile [2n][128g][32k] goes through 36KB padded LDS (stride 36 floats), ONE
// post-compute barrier, then g-major cooperative stores: 4 x 256B segments/instr.
// att stores stay direct (already 256B runs). x/W/a_pair access identical to R8.

#define NK 32768
#define NEG_SLOPE 0.2f
#define LSTR 36                     // LDS k-stride (floats); 16B-aligned, bank-optimal

using f32x4 = __attribute__((ext_vector_type(4))) float;
using s16x8 = __attribute__((ext_vector_type(8))) short;

__global__ __launch_bounds__(256, 4) void fused_gat_wave(
    const float* __restrict__ x,
    const int*   __restrict__ core_types,
    const int*   __restrict__ target_types,
    const float* __restrict__ W,
    const float* __restrict__ a_pair,
    float* __restrict__ out,
    float* __restrict__ att_out)
{
    __shared__ float lds[2 * 128 * LSTR];     // 36864 B: [nl][g][k(pad 36)]

    const int t    = threadIdx.x;
    const int lane = t & 63, l15 = lane & 15, l4 = lane >> 4;
    const int wv   = t >> 6;                  // 0..3
    const int nl   = wv >> 1, half = wv & 1;  // wave -> (n-local, g-half)
    const int b    = blockIdx.x >> 9;
    const int n0   = (blockIdx.x & 511) * 2;
    const int n    = n0 + nl;

    const float* xb = x + (size_t)b * 128 * NK + n * 32;   // + f*NK + k
    const int    g0 = half * 64 + 4 * l15;                 // lane's base g; g = g0 + gt
    const float* wb = W + g0;                              // + f*128

    // ---- MFMA fs-loop: acc[mt][gt], k = 16mt + l4*4 + r, g = g0 + gt
    f32x4 acc[2][4];
    #pragma unroll
    for (int mt = 0; mt < 2; ++mt)
        #pragma unroll
        for (int gt = 0; gt < 4; ++gt) acc[mt][gt] = (f32x4){0.f, 0.f, 0.f, 0.f};

    #pragma unroll
    for (int fs = 0; fs < 4; ++fs) {
        const int f0 = fs * 32 + l4 * 8;

        // W: one float4 per f-row (covers gt=0..3), repack to bf16 fragments
        s16x8 bfrag[4];
        #pragma unroll
        for (int fp = 0; fp < 4; ++fp) {                   // f = f0 + 2fp (+1)
            const f32x4 we = *(const f32x4*)&wb[(size_t)(f0 + 2 * fp)     * 128];
            const f32x4 wo = *(const f32x4*)&wb[(size_t)(f0 + 2 * fp + 1) * 128];
            #pragma unroll
            for (int gt = 0; gt < 4; ++gt) {
                __hip_bfloat162 h2 = __float22bfloat162_rn(make_float2(we[gt], wo[gt]));
                ((unsigned*)&bfrag[gt])[fp] = *(const unsigned*)&h2;
            }
        }

        s16x8 afrag[2];
        #pragma unroll
        for (int mt = 0; mt < 2; ++mt)
            #pragma unroll
            for (int i2 = 0; i2 < 4; ++i2) {
                const int f = f0 + 2 * i2;
                __hip_bfloat162 h2 = __float22bfloat162_rn(make_float2(
                    xb[(size_t)f * NK + 16 * mt + l15],
                    xb[(size_t)(f + 1) * NK + 16 * mt + l15]));
                ((unsigned*)&afrag[mt])[i2] = *(const unsigned*)&h2;
            }

        #pragma unroll
        for (int mt = 0; mt < 2; ++mt)
            #pragma unroll
            for (int gt = 0; gt < 4; ++gt)
                acc[mt][gt] = __builtin_amdgcn_mfma_f32_16x16x32_bf16(
                    afrag[mt], bfrag[gt], acc[mt][gt], 0, 0, 0);
    }

    // ---- e = leaky_relu(Wh * a)   (a_pair: one float4 per (mt,r))
    const int cc = core_types[b * 1024 + n];
    float ev[2][4][4];
    #pragma unroll
    for (int mt = 0; mt < 2; ++mt) {
        const int kb = 16 * mt + l4 * 4;
        const int4 tt4 = *(const int4*)&target_types[((size_t)(b * 1024 + n)) * 32 + kb];
        const int ttv[4] = {tt4.x, tt4.y, tt4.z, tt4.w};
        #pragma unroll
        for (int r = 0; r < 4; ++r) {
            const int tv = ttv[r];
            const int lo = min(cc, tv), hi = max(cc, tv);
            const int idx = lo * (17 - lo) / 2 + (hi - lo);
            const f32x4 a4 = *(const f32x4*)&a_pair[idx * 128 + g0];
            #pragma unroll
            for (int gt = 0; gt < 4; ++gt) {
                const float e = acc[mt][gt][r] * a4[gt];
                ev[mt][gt][r] = e > 0.f ? e : NEG_SLOPE * e;
            }
        }
    }

    // ---- softmax over k (8 regs x 4-lane group: xor 16, 32), per gt
    #pragma unroll
    for (int gt = 0; gt < 4; ++gt) {
        float mx = -1e30f;
        #pragma unroll
        for (int mt = 0; mt < 2; ++mt)
            #pragma unroll
            for (int r = 0; r < 4; ++r) mx = fmaxf(mx, ev[mt][gt][r]);
        mx = fmaxf(mx, __shfl_xor(mx, 16));
        mx = fmaxf(mx, __shfl_xor(mx, 32));
        float sm = 0.f;
        #pragma unroll
        for (int mt = 0; mt < 2; ++mt)
            #pragma unroll
            for (int r = 0; r < 4; ++r) {
                const float p = __expf(ev[mt][gt][r] - mx);
                ev[mt][gt][r] = p;
                sm += p;
            }
        sm += __shfl_xor(sm, 16);
        sm += __shfl_xor(sm, 32);
        const float inv = __fdividef(1.f, sm);
        #pragma unroll
        for (int mt = 0; mt < 2; ++mt)
            #pragma unroll
            for (int r = 0; r < 4; ++r) ev[mt][gt][r] *= inv;
    }

    // ---- att stores direct (256B runs, non-temporal)
    #pragma unroll
    for (int mt = 0; mt < 2; ++mt) {
        const int kb = 16 * mt + l4 * 4;
        #pragma unroll
        for (int r = 0; r < 4; ++r) {
            f32x4 av = {ev[mt][0][r], ev[mt][1][r], ev[mt][2][r], ev[mt][3][r]};
            __builtin_nontemporal_store(
                av, (f32x4*)&att_out[(((size_t)(b * 1024 + n)) * 32 + kb + r) * 128 + g0]);
        }
    }

    // ---- out values -> LDS [nl][g][k] (pad 36: all phases bank-throughput-optimal)
    #pragma unroll
    for (int mt = 0; mt < 2; ++mt) {
        const int kb = 16 * mt + l4 * 4;
        #pragma unroll
        for (int gt = 0; gt < 4; ++gt) {
            f32x4 ov;
            #pragma unroll
            for (int r = 0; r < 4; ++r) {
                const float hh = ev[mt][gt][r] * acc[mt][gt][r];
                ov[r] = hh > 0.f ? hh : __expf(hh) - 1.f;
            }
            *(f32x4*)&lds[(nl * 128 + g0 + gt) * LSTR + kb] = ov;
        }
    }

    __syncthreads();

    // ---- cooperative g-major out stores: per instr 4 x 256B contiguous segments
    {
        const int hi  = t >> 4;          // 0..15 : g sub-index
        const int nl2 = (t >> 3) & 1;    // n-local
        const int kq  = (t & 7) * 4;     // k quad
        float* ob = out + (size_t)b * 128 * NK + (size_t)(n0 + nl2) * 32 + kq;
        #pragma unroll
        for (int i = 0; i < 8; ++i) {
            const int g = i * 16 + hi;
            const f32x4 v = *(const f32x4*)&lds[(nl2 * 128 + g) * LSTR + kq];
            __builtin_nontemporal_store(v, (f32x4*)&ob[(size_t)g * NK]);
        }
    }
}

extern "C" void kernel_launch(void* const* d_in, const int* in_sizes, int n_in,
                              void* d_out, int out_size, void* d_ws, size_t ws_size,
                              hipStream_t stream) {
    const float* x    = (const float*)d_in[0];
    const int*   core = (const int*)  d_in[1];
    const int*   tgt  = (const int*)  d_in[2];
    const float* W    = (const float*)d_in[3];
    const float* ap   = (const float*)d_in[4];
    // d_in[5]/d_in[6] (lin_w, lin_b) only feed attention_viz, which is not returned.

    float* out_p = (float*)d_out;                       // (8,128,1024,32)
    float* att_p = out_p + (size_t)8 * 128 * 1024 * 32; // (8,1024,32,128)

    fused_gat_wave<<<dim3(4096), dim3(256), 0, stream>>>(x, core, tgt, W, ap, out_p, att_p);
}